// Round 2
// baseline (326.666 us; speedup 1.0000x reference)
//
#include <hip/hip_runtime.h>
#include <hip/hip_bf16.h>
#include <stdint.h>

// MultiHeadAttention forward, MI355X/gfx950.
// Pipeline: cvt x->bf16 | cvt+transpose W->bf16 B^T | fused QKV GEMM (bf16 MFMA,
//           Q pre-scaled by 1/sqrt(dk)*log2e) | transpose V per-head |
//           flash attention (exp2-domain online softmax, ones-MFMA row sums,
//           defer-max, XOR-swizzled LDS) | out GEMM.
// Workspace layout (needs 56 MiB):
//   xb 0..8M | Wt(QKVO) 8..16M | Qb 16..24M | Kb 24..32M | Vb 32..40M
//   | Vt 40..48M | ctx 48..56M

#define DM 1024
#define SEQ 4096
#define NH 16
#define DK 64

// 1/sqrt(64) * log2(e): scores come out of QK^T already in exp2 domain.
#define QSCALE 0.18033688011112042f

typedef __attribute__((ext_vector_type(8))) short bf16x8;
typedef __attribute__((ext_vector_type(4))) float f32x4;

__device__ __forceinline__ short f2bf(float f) {
  union { float f; uint32_t u; } x; x.f = f;
  uint32_t r = x.u + 0x7fffu + ((x.u >> 16) & 1u);
  return (short)(r >> 16);
}

__device__ __forceinline__ void gl_lds16(const void* g, void* l) {
  __builtin_amdgcn_global_load_lds(
      (const __attribute__((address_space(1))) void*)g,
      (__attribute__((address_space(3))) void*)l, 16, 0, 0);
}

// ---------- fp32 -> bf16 (x) ----------
__global__ __launch_bounds__(256) void cvt_x_k(const float* __restrict__ in,
                                               short* __restrict__ out) {
  size_t i = (size_t)blockIdx.x * 256 + threadIdx.x;
  const float4* ip = (const float4*)in;
  float4 a = ip[2 * i], b = ip[2 * i + 1];
  bf16x8 o;
  o[0] = f2bf(a.x); o[1] = f2bf(a.y); o[2] = f2bf(a.z); o[3] = f2bf(a.w);
  o[4] = f2bf(b.x); o[5] = f2bf(b.y); o[6] = f2bf(b.z); o[7] = f2bf(b.w);
  *(bf16x8*)(out + 8 * i) = o;
}

// ---------- W [k][n] fp32 -> Wt [n][k] bf16 (tiled transpose), z = which W ----------
__global__ __launch_bounds__(256) void cvt_wt_k(const float* __restrict__ W0,
                                                const float* __restrict__ W1,
                                                const float* __restrict__ W2,
                                                const float* __restrict__ W3,
                                                short* __restrict__ Wt0) {
  __shared__ alignas(16) short T[64][66];
  const int z = blockIdx.z;
  const float* W = (z == 0) ? W0 : (z == 1) ? W1 : (z == 2) ? W2 : W3;
  short* Wt = Wt0 + (size_t)z * (DM * DM);
  const int k0 = blockIdx.y * 64, n0 = blockIdx.x * 64;
#pragma unroll
  for (int rep = 0; rep < 16; ++rep) {
    int lin = rep * 256 + threadIdx.x;
    int i = lin >> 6, j = lin & 63;
    T[i][j] = f2bf(W[(size_t)(k0 + i) * DM + n0 + j]);
  }
  __syncthreads();
#pragma unroll
  for (int rep = 0; rep < 16; ++rep) {
    int lin = rep * 256 + threadIdx.x;
    int n = lin >> 6, kk = lin & 63;
    Wt[(size_t)(n0 + n) * DM + k0 + kk] = T[kk][n];
  }
}

// ---------- V [s][h*64+d] bf16 -> Vt [h*64+d][s] bf16 ----------
__global__ __launch_bounds__(256) void trans_v_k(const short* __restrict__ V,
                                                 short* __restrict__ Vt) {
  __shared__ alignas(16) short T[64][66];
  const int s0 = blockIdx.x * 64, h = blockIdx.y;
#pragma unroll
  for (int rep = 0; rep < 16; ++rep) {
    int lin = rep * 256 + threadIdx.x;
    int i = lin >> 6, j = lin & 63;
    T[i][j] = V[(size_t)(s0 + i) * DM + h * DK + j];
  }
  __syncthreads();
#pragma unroll
  for (int rep = 0; rep < 16; ++rep) {
    int lin = rep * 256 + threadIdx.x;
    int d = lin >> 6, ss = lin & 63;
    Vt[((size_t)h * DK + d) * SEQ + s0 + ss] = T[ss][d];
  }
}

// ---------- fused QKV GEMM: out[z] = xb @ Wt[z]^T + b[z], bf16 out ----------
// A row-major [M][K] bf16, Bt row-major [N][K] bf16. 128x128 tile, BK=32.
// z==0 (Q) output scaled by QSCALE.
__global__ __launch_bounds__(256) void gemm_qkv(
    const short* __restrict__ xb, const short* __restrict__ Wt0,
    const float* __restrict__ bq, const float* __restrict__ bk,
    const float* __restrict__ bv, short* __restrict__ out0) {
  const int z = blockIdx.z;
  const short* Bt = Wt0 + (size_t)z * (DM * DM);
  const float* bias = (z == 0) ? bq : (z == 1) ? bk : bv;
  const float qs = (z == 0) ? QSCALE : 1.0f;
  short* out = out0 + (size_t)z * ((size_t)SEQ * DM);

  __shared__ alignas(16) short As[128 * 32];
  __shared__ alignas(16) short Bs[128 * 32];
  const int tid = threadIdx.x, lane = tid & 63, w = tid >> 6;
  const int bm = blockIdx.y * 128, bn = blockIdx.x * 128;
  const int wm = (w >> 1) * 64, wn = (w & 1) * 64;
  f32x4 acc[4][4] = {};

  for (int kt = 0; kt < DM; kt += 32) {
    __syncthreads();
#pragma unroll
    for (int c = 0; c < 2; ++c) {
      int i = w * 2 + c;
      int ob = i * 1024 + lane * 16;
      int row = ob >> 6, colb = ob & 63;
      gl_lds16((const char*)xb + ((size_t)(bm + row) * DM + kt) * 2 + colb,
               (char*)As + i * 1024);
      gl_lds16((const char*)Bt + ((size_t)(bn + row) * DM + kt) * 2 + colb,
               (char*)Bs + i * 1024);
    }
    __syncthreads();
    bf16x8 bfr[4];
#pragma unroll
    for (int n = 0; n < 4; ++n)
      bfr[n] = *(const bf16x8*)((const char*)Bs +
                                (wn + n * 16 + (lane & 15)) * 64 + (lane >> 4) * 16);
#pragma unroll
    for (int m = 0; m < 4; ++m) {
      bf16x8 af = *(const bf16x8*)((const char*)As +
                                   (wm + m * 16 + (lane & 15)) * 64 + (lane >> 4) * 16);
#pragma unroll
      for (int n = 0; n < 4; ++n)
        acc[m][n] = __builtin_amdgcn_mfma_f32_16x16x32_bf16(af, bfr[n], acc[m][n], 0, 0, 0);
    }
  }
  const int r0 = bm + wm + ((lane >> 4) << 2);
  const int c0 = bn + wn + (lane & 15);
#pragma unroll
  for (int n = 0; n < 4; ++n) {
    const int col = c0 + n * 16;
    const float b = bias[col];
#pragma unroll
    for (int m = 0; m < 4; ++m)
#pragma unroll
      for (int r = 0; r < 4; ++r)
        out[(size_t)(r0 + m * 16 + r) * DM + col] = f2bf((acc[m][n][r] + b) * qs);
  }
}

// ---------- output GEMM: out = ctx @ WtO^T + b_o, fp32 out ----------
__global__ __launch_bounds__(256) void gemm_out(
    const short* __restrict__ A, const short* __restrict__ Bt,
    const float* __restrict__ bias, float* __restrict__ out) {
  __shared__ alignas(16) short As[128 * 32];
  __shared__ alignas(16) short Bs[128 * 32];
  const int tid = threadIdx.x, lane = tid & 63, w = tid >> 6;
  const int bm = blockIdx.y * 128, bn = blockIdx.x * 128;
  const int wm = (w >> 1) * 64, wn = (w & 1) * 64;
  f32x4 acc[4][4] = {};

  for (int kt = 0; kt < DM; kt += 32) {
    __syncthreads();
#pragma unroll
    for (int c = 0; c < 2; ++c) {
      int i = w * 2 + c;
      int ob = i * 1024 + lane * 16;
      int row = ob >> 6, colb = ob & 63;
      gl_lds16((const char*)A + ((size_t)(bm + row) * DM + kt) * 2 + colb,
               (char*)As + i * 1024);
      gl_lds16((const char*)Bt + ((size_t)(bn + row) * DM + kt) * 2 + colb,
               (char*)Bs + i * 1024);
    }
    __syncthreads();
    bf16x8 bfr[4];
#pragma unroll
    for (int n = 0; n < 4; ++n)
      bfr[n] = *(const bf16x8*)((const char*)Bs +
                                (wn + n * 16 + (lane & 15)) * 64 + (lane >> 4) * 16);
#pragma unroll
    for (int m = 0; m < 4; ++m) {
      bf16x8 af = *(const bf16x8*)((const char*)As +
                                   (wm + m * 16 + (lane & 15)) * 64 + (lane >> 4) * 16);
#pragma unroll
      for (int n = 0; n < 4; ++n)
        acc[m][n] = __builtin_amdgcn_mfma_f32_16x16x32_bf16(af, bfr[n], acc[m][n], 0, 0, 0);
    }
  }
  const int r0 = bm + wm + ((lane >> 4) << 2);
  const int c0 = bn + wn + (lane & 15);
#pragma unroll
  for (int n = 0; n < 4; ++n) {
    const int col = c0 + n * 16;
    const float b = bias[col];
#pragma unroll
    for (int m = 0; m < 4; ++m)
#pragma unroll
      for (int r = 0; r < 4; ++r)
        out[(size_t)(r0 + m * 16 + r) * DM + col] = acc[m][n][r] + b;
  }
}

// ---------- flash attention ----------
// Q pre-scaled so scores are in exp2 domain. K/V/P LDS tiles XOR-swizzled
// (byte ^= (row&7)<<4) to kill 16-way bank conflicts on ds_read_b128;
// K/V achieve this via pre-swizzled global source (gl_lds dest must be linear).
// Row-sums computed by an extra MFMA against a ones B-fragment (result is
// replicated across all lanes of the row). Defer-max: skip o-rescale while
// per-tile max growth <= 8 (P bounded by 2^8, fp32 accum safe).
__global__ __launch_bounds__(256) void attn_k(
    const short* __restrict__ Qb, const short* __restrict__ Kb,
    const short* __restrict__ Vt, short* __restrict__ ctx) {
  const int h = blockIdx.y, qt = blockIdx.x;
  const int tid = threadIdx.x, lane = tid & 63, w = tid >> 6;
  __shared__ alignas(16) short Ks[64 * 64];      // [s][d] swizzled, 128 B rows
  __shared__ alignas(16) short Vs[64 * 64];      // [d][s] swizzled, 128 B rows
  __shared__ alignas(16) short Pl[4][16 * 64];   // per-wave P [16 q][64 s] swizzled

  const int qr = qt * 64 + w * 16 + (lane & 15);
  const short* qp = Qb + (size_t)qr * DM + h * DK + ((lane >> 4) * 8);
  const bf16x8 qf0 = *(const bf16x8*)qp;
  const bf16x8 qf1 = *(const bf16x8*)(qp + 32);

  bf16x8 ones;
#pragma unroll
  for (int j = 0; j < 8; ++j) ones[j] = (short)0x3F80;

  f32x4 o[4] = {};
  f32x4 ol = {};                     // row sums (all lanes of a row identical)
  float mr[4];
#pragma unroll
  for (int r = 0; r < 4; ++r) mr[r] = -1e30f;

  const int xk = (lane & 7) << 4;    // read-side XOR (row&7 == lane&7)
  char* pbase = (char*)&Pl[w][0];
  const int q2 = (lane & 15) * 2;

  for (int s0 = 0; s0 < SEQ; s0 += 64) {
    __syncthreads();  // prior iteration's LDS reads done
#pragma unroll
    for (int c = 0; c < 2; ++c) {
      int i = w * 2 + c;
      int ob = i * 1024 + lane * 16;
      int row = ob >> 7, colb = ob & 127;
      int src = colb ^ ((row & 7) << 4);   // inverse-swizzle the SOURCE
      gl_lds16((const char*)Kb + ((size_t)(s0 + row) * DM + h * DK) * 2 + src,
               (char*)Ks + i * 1024);
      gl_lds16((const char*)Vt + ((size_t)(h * DK + row) * SEQ + s0) * 2 + src,
               (char*)Vs + i * 1024);
    }
    __syncthreads();

    // S' = Qs K^T (already exp2-domain scaled)
    f32x4 sc[4] = {};
    __builtin_amdgcn_s_setprio(1);
#pragma unroll
    for (int kk = 0; kk < 2; ++kk) {
      bf16x8 a = kk ? qf1 : qf0;
#pragma unroll
      for (int n = 0; n < 4; ++n) {
        bf16x8 b = *(const bf16x8*)((const char*)Ks + (n * 16 + (lane & 15)) * 128 +
                                    ((kk * 64 + (lane >> 4) * 16) ^ xk));
        sc[n] = __builtin_amdgcn_mfma_f32_16x16x32_bf16(a, b, sc[n], 0, 0, 0);
      }
    }
    __builtin_amdgcn_s_setprio(0);

    // online softmax, exp2 domain; row = (lane>>4)*4 + r
    float mx[4];
#pragma unroll
    for (int r = 0; r < 4; ++r) {
      float m = fmaxf(fmaxf(sc[0][r], sc[1][r]), fmaxf(sc[2][r], sc[3][r]));
      m = fmaxf(m, __shfl_xor(m, 1));
      m = fmaxf(m, __shfl_xor(m, 2));
      m = fmaxf(m, __shfl_xor(m, 4));
      m = fmaxf(m, __shfl_xor(m, 8));
      mx[r] = m;
    }
    bool ok = (mx[0] <= mr[0] + 8.f) & (mx[1] <= mr[1] + 8.f) &
              (mx[2] <= mr[2] + 8.f) & (mx[3] <= mr[3] + 8.f);
    if (!__all(ok)) {
#pragma unroll
      for (int r = 0; r < 4; ++r) {
        float mnew = fmaxf(mr[r], mx[r]);
        float alpha = exp2f(mr[r] - mnew);
        mr[r] = mnew;
        o[0][r] *= alpha; o[1][r] *= alpha; o[2][r] *= alpha; o[3][r] *= alpha;
        ol[r] *= alpha;
      }
    }
#pragma unroll
    for (int r = 0; r < 4; ++r) {
      const int prow = (lane >> 4) * 4 + r;
      char* pr = pbase + prow * 128;
      const int X = (prow & 7) << 4;
#pragma unroll
      for (int n = 0; n < 4; ++n) {
        float p = exp2f(sc[n][r] - mr[r]);
        *(short*)(pr + ((n * 32 + q2) ^ X)) = f2bf(p);
      }
    }

    // O += P V ; l += P 1  (A-frag from swizzled Pl, B-frag from swizzled Vs)
    __builtin_amdgcn_s_setprio(1);
#pragma unroll
    for (int kk = 0; kk < 2; ++kk) {
      bf16x8 pa = *(const bf16x8*)(pbase + (lane & 15) * 128 +
                                   ((kk * 64 + (lane >> 4) * 16) ^ xk));
      ol = __builtin_amdgcn_mfma_f32_16x16x32_bf16(pa, ones, ol, 0, 0, 0);
#pragma unroll
      for (int n = 0; n < 4; ++n) {
        bf16x8 vb = *(const bf16x8*)((const char*)Vs + (n * 16 + (lane & 15)) * 128 +
                                     ((kk * 64 + (lane >> 4) * 16) ^ xk));
        o[n] = __builtin_amdgcn_mfma_f32_16x16x32_bf16(pa, vb, o[n], 0, 0, 0);
      }
    }
    __builtin_amdgcn_s_setprio(0);
  }

#pragma unroll
  for (int r = 0; r < 4; ++r) {
    float inv = 1.f / ol[r];
    int row = qt * 64 + w * 16 + (lane >> 4) * 4 + r;
#pragma unroll
    for (int n = 0; n < 4; ++n)
      ctx[(size_t)row * DM + h * DK + n * 16 + (lane & 15)] = f2bf(o[n][r] * inv);
  }
}

extern "C" void kernel_launch(void* const* d_in, const int* in_sizes, int n_in,
                              void* d_out, int out_size, void* d_ws, size_t ws_size,
                              hipStream_t stream) {
  const float* x  = (const float*)d_in[0];
  const float* Wq = (const float*)d_in[1];
  const float* bq = (const float*)d_in[2];
  const float* Wk = (const float*)d_in[3];
  const float* bk = (const float*)d_in[4];
  const float* Wv = (const float*)d_in[5];
  const float* bv = (const float*)d_in[6];
  const float* Wo = (const float*)d_in[7];
  const float* bo = (const float*)d_in[8];

  char* ws = (char*)d_ws;
  short* xb  = (short*)(ws + (size_t)0);
  short* Wt  = (short*)(ws + ((size_t)8 << 20));
  short* Qb  = (short*)(ws + ((size_t)16 << 20));
  short* Kb  = (short*)(ws + ((size_t)24 << 20));
  short* Vb  = (short*)(ws + ((size_t)32 << 20));
  short* Vt  = (short*)(ws + ((size_t)40 << 20));
  short* ctx = (short*)(ws + ((size_t)48 << 20));
  (void)Vb;

  cvt_x_k<<<2048, 256, 0, stream>>>(x, xb);
  cvt_wt_k<<<dim3(16, 16, 4), 256, 0, stream>>>(Wq, Wk, Wv, Wo, Wt);
  gemm_qkv<<<dim3(DM / 128, SEQ / 128, 3), 256, 0, stream>>>(xb, Wt, bq, bk, bv, Qb);
  trans_v_k<<<dim3(SEQ / 64, NH), 256, 0, stream>>>(Vb, Vt);
  attn_k<<<dim3(SEQ / 64, NH), 256, 0, stream>>>(Qb, Kb, Vt, ctx);
  gemm_out<<<dim3(DM / 128, SEQ / 128), 256, 0, stream>>>(
      ctx, Wt + (size_t)3 * (DM * DM), bo, (float*)d_out);
}

// Round 3
// 291.444 us; speedup vs baseline: 1.1209x; 1.1209x over previous
//
#include <hip/hip_runtime.h>
#include <hip/hip_bf16.h>
#include <stdint.h>

// MultiHeadAttention forward, MI355X/gfx950.
// Pipeline: cvt x->bf16 | cvt+transpose W->bf16 B^T | fused QKV GEMM (bf16 MFMA,
//           Q pre-scaled by 1/sqrt(dk)*log2e) | transpose V per-head (sigma-permuted
//           columns) | flash attention (exp2-domain online softmax, group-shared max,
//           ones-MFMA row sums, cvt_pk packed P stores, double-buffered K/V,
//           XOR-swizzled LDS) | out GEMM.
// Workspace layout (needs 56 MiB):
//   xb 0..8M | Wt(QKVO) 8..16M | Qb 16..24M | Kb 24..32M | Vb 32..40M
//   | Vt 40..48M | ctx 48..56M

#define DM 1024
#define SEQ 4096
#define NH 16
#define DK 64

// 1/sqrt(64) * log2(e): scores come out of QK^T already in exp2 domain.
#define QSCALE 0.18033688011112042f

typedef __attribute__((ext_vector_type(8))) short bf16x8;
typedef __attribute__((ext_vector_type(4))) float f32x4;
typedef __attribute__((ext_vector_type(2))) uint32_t u32x2;

__device__ __forceinline__ short f2bf(float f) {
  union { float f; uint32_t u; } x; x.f = f;
  uint32_t r = x.u + 0x7fffu + ((x.u >> 16) & 1u);
  return (short)(r >> 16);
}

__device__ __forceinline__ void gl_lds16(const void* g, void* l) {
  __builtin_amdgcn_global_load_lds(
      (const __attribute__((address_space(1))) void*)g,
      (__attribute__((address_space(3))) void*)l, 16, 0, 0);
}

// ---------- fp32 -> bf16 (x) ----------
__global__ __launch_bounds__(256) void cvt_x_k(const float* __restrict__ in,
                                               short* __restrict__ out) {
  size_t i = (size_t)blockIdx.x * 256 + threadIdx.x;
  const float4* ip = (const float4*)in;
  float4 a = ip[2 * i], b = ip[2 * i + 1];
  bf16x8 o;
  o[0] = f2bf(a.x); o[1] = f2bf(a.y); o[2] = f2bf(a.z); o[3] = f2bf(a.w);
  o[4] = f2bf(b.x); o[5] = f2bf(b.y); o[6] = f2bf(b.z); o[7] = f2bf(b.w);
  *(bf16x8*)(out + 8 * i) = o;
}

// ---------- W [k][n] fp32 -> Wt [n][k] bf16 (tiled transpose), z = which W ----------
__global__ __launch_bounds__(256) void cvt_wt_k(const float* __restrict__ W0,
                                                const float* __restrict__ W1,
                                                const float* __restrict__ W2,
                                                const float* __restrict__ W3,
                                                short* __restrict__ Wt0) {
  __shared__ alignas(16) short T[64][66];
  const int z = blockIdx.z;
  const float* W = (z == 0) ? W0 : (z == 1) ? W1 : (z == 2) ? W2 : W3;
  short* Wt = Wt0 + (size_t)z * (DM * DM);
  const int k0 = blockIdx.y * 64, n0 = blockIdx.x * 64;
#pragma unroll
  for (int rep = 0; rep < 16; ++rep) {
    int lin = rep * 256 + threadIdx.x;
    int i = lin >> 6, j = lin & 63;
    T[i][j] = f2bf(W[(size_t)(k0 + i) * DM + n0 + j]);
  }
  __syncthreads();
#pragma unroll
  for (int rep = 0; rep < 16; ++rep) {
    int lin = rep * 256 + threadIdx.x;
    int n = lin >> 6, kk = lin & 63;
    Wt[(size_t)(n0 + n) * DM + k0 + kk] = T[kk][n];
  }
}

// ---------- V [s][h*64+d] bf16 -> Vt [h*64+d][s] bf16, sigma-permuted columns ----
// Within each 64-column block, value for kv index (s0+c) is stored at
// s0 + sigma(c), sigma(c) = 4*(c&15) + (c>>4).  This matches the P-store
// layout in attn_k so PV's operands agree on column order.
__global__ __launch_bounds__(256) void trans_v_k(const short* __restrict__ V,
                                                 short* __restrict__ Vt) {
  __shared__ alignas(16) short T[64][66];
  const int s0 = blockIdx.x * 64, h = blockIdx.y;
#pragma unroll
  for (int rep = 0; rep < 16; ++rep) {
    int lin = rep * 256 + threadIdx.x;
    int i = lin >> 6, j = lin & 63;
    T[i][j] = V[(size_t)(s0 + i) * DM + h * DK + j];
  }
  __syncthreads();
#pragma unroll
  for (int rep = 0; rep < 16; ++rep) {
    int lin = rep * 256 + threadIdx.x;
    int d = lin >> 6, ss = lin & 63;
    int sp = ((ss & 15) << 2) + (ss >> 4);   // sigma(ss)
    Vt[((size_t)h * DK + d) * SEQ + s0 + sp] = T[ss][d];
  }
}

// ---------- fused QKV GEMM: out[z] = xb @ Wt[z]^T + b[z], bf16 out ----------
__global__ __launch_bounds__(256) void gemm_qkv(
    const short* __restrict__ xb, const short* __restrict__ Wt0,
    const float* __restrict__ bq, const float* __restrict__ bk,
    const float* __restrict__ bv, short* __restrict__ out0) {
  const int z = blockIdx.z;
  const short* Bt = Wt0 + (size_t)z * (DM * DM);
  const float* bias = (z == 0) ? bq : (z == 1) ? bk : bv;
  const float qs = (z == 0) ? QSCALE : 1.0f;
  short* out = out0 + (size_t)z * ((size_t)SEQ * DM);

  __shared__ alignas(16) short As[128 * 32];
  __shared__ alignas(16) short Bs[128 * 32];
  const int tid = threadIdx.x, lane = tid & 63, w = tid >> 6;
  const int bm = blockIdx.y * 128, bn = blockIdx.x * 128;
  const int wm = (w >> 1) * 64, wn = (w & 1) * 64;
  f32x4 acc[4][4] = {};

  for (int kt = 0; kt < DM; kt += 32) {
    __syncthreads();
#pragma unroll
    for (int c = 0; c < 2; ++c) {
      int i = w * 2 + c;
      int ob = i * 1024 + lane * 16;
      int row = ob >> 6, colb = ob & 63;
      gl_lds16((const char*)xb + ((size_t)(bm + row) * DM + kt) * 2 + colb,
               (char*)As + i * 1024);
      gl_lds16((const char*)Bt + ((size_t)(bn + row) * DM + kt) * 2 + colb,
               (char*)Bs + i * 1024);
    }
    __syncthreads();
    bf16x8 bfr[4];
#pragma unroll
    for (int n = 0; n < 4; ++n)
      bfr[n] = *(const bf16x8*)((const char*)Bs +
                                (wn + n * 16 + (lane & 15)) * 64 + (lane >> 4) * 16);
#pragma unroll
    for (int m = 0; m < 4; ++m) {
      bf16x8 af = *(const bf16x8*)((const char*)As +
                                   (wm + m * 16 + (lane & 15)) * 64 + (lane >> 4) * 16);
#pragma unroll
      for (int n = 0; n < 4; ++n)
        acc[m][n] = __builtin_amdgcn_mfma_f32_16x16x32_bf16(af, bfr[n], acc[m][n], 0, 0, 0);
    }
  }
  const int r0 = bm + wm + ((lane >> 4) << 2);
  const int c0 = bn + wn + (lane & 15);
#pragma unroll
  for (int n = 0; n < 4; ++n) {
    const int col = c0 + n * 16;
    const float b = bias[col];
#pragma unroll
    for (int m = 0; m < 4; ++m)
#pragma unroll
      for (int r = 0; r < 4; ++r)
        out[(size_t)(r0 + m * 16 + r) * DM + col] = f2bf((acc[m][n][r] + b) * qs);
  }
}

// ---------- output GEMM: out = ctx @ WtO^T + b_o, fp32 out ----------
__global__ __launch_bounds__(256) void gemm_out(
    const short* __restrict__ A, const short* __restrict__ Bt,
    const float* __restrict__ bias, float* __restrict__ out) {
  __shared__ alignas(16) short As[128 * 32];
  __shared__ alignas(16) short Bs[128 * 32];
  const int tid = threadIdx.x, lane = tid & 63, w = tid >> 6;
  const int bm = blockIdx.y * 128, bn = blockIdx.x * 128;
  const int wm = (w >> 1) * 64, wn = (w & 1) * 64;
  f32x4 acc[4][4] = {};

  for (int kt = 0; kt < DM; kt += 32) {
    __syncthreads();
#pragma unroll
    for (int c = 0; c < 2; ++c) {
      int i = w * 2 + c;
      int ob = i * 1024 + lane * 16;
      int row = ob >> 6, colb = ob & 63;
      gl_lds16((const char*)A + ((size_t)(bm + row) * DM + kt) * 2 + colb,
               (char*)As + i * 1024);
      gl_lds16((const char*)Bt + ((size_t)(bn + row) * DM + kt) * 2 + colb,
               (char*)Bs + i * 1024);
    }
    __syncthreads();
    bf16x8 bfr[4];
#pragma unroll
    for (int n = 0; n < 4; ++n)
      bfr[n] = *(const bf16x8*)((const char*)Bs +
                                (wn + n * 16 + (lane & 15)) * 64 + (lane >> 4) * 16);
#pragma unroll
    for (int m = 0; m < 4; ++m) {
      bf16x8 af = *(const bf16x8*)((const char*)As +
                                   (wm + m * 16 + (lane & 15)) * 64 + (lane >> 4) * 16);
#pragma unroll
      for (int n = 0; n < 4; ++n)
        acc[m][n] = __builtin_amdgcn_mfma_f32_16x16x32_bf16(af, bfr[n], acc[m][n], 0, 0, 0);
    }
  }
  const int r0 = bm + wm + ((lane >> 4) << 2);
  const int c0 = bn + wn + (lane & 15);
#pragma unroll
  for (int n = 0; n < 4; ++n) {
    const int col = c0 + n * 16;
    const float b = bias[col];
#pragma unroll
    for (int m = 0; m < 4; ++m)
#pragma unroll
      for (int r = 0; r < 4; ++r)
        out[(size_t)(r0 + m * 16 + r) * DM + col] = acc[m][n][r] + b;
  }
}

// ---------- flash attention ----------
// Q pre-scaled -> scores in exp2 domain.  K/V double-buffered in LDS, staged
// with pre-swizzled global source (byte ^= (row&7)<<4) so ds_read_b128 is
// conflict-free.  Online softmax with a 4-row lane-group SHARED max (exact:
// P and l scale by the same factor, O=o/l unchanged) -> one v_max3 tree +
// 4 shfl_xor per tile.  Row sums by ones-MFMA.  P packed via
// v_cvt_pk_bf16_f32 into sigma-permuted columns (col'=4*(c&15)+(c>>4)) so
// each lane's 4 values per row form one ds_write_b64; V columns carry the
// same sigma (see trans_v_k).  Defer-max: skip o-rescale while tile max
// growth <= 8 (P bounded by 2^8).
__global__ __launch_bounds__(256) void attn_k(
    const short* __restrict__ Qb, const short* __restrict__ Kb,
    const short* __restrict__ Vt, short* __restrict__ ctx) {
  const int h = blockIdx.y, qt = blockIdx.x;
  const int tid = threadIdx.x, lane = tid & 63, w = tid >> 6;
  __shared__ alignas(16) short Ks[2][64 * 64];   // [s][d] swizzled
  __shared__ alignas(16) short Vs[2][64 * 64];   // [d][s'] swizzled, sigma cols
  __shared__ alignas(16) short Pl[4][16 * 64];   // per-wave P [16 q][64 s'] swizzled

  const int qr = qt * 64 + w * 16 + (lane & 15);
  const short* qp = Qb + (size_t)qr * DM + h * DK + ((lane >> 4) * 8);
  const bf16x8 qf0 = *(const bf16x8*)qp;
  const bf16x8 qf1 = *(const bf16x8*)(qp + 32);

  bf16x8 ones;
#pragma unroll
  for (int j = 0; j < 8; ++j) ones[j] = (short)0x3F80;

  f32x4 o[4] = {};
  f32x4 ol = {};                    // row sums (replicated across row's lanes)
  float m = -3000.f;                // group-shared running max (exp2 domain)

  const int xk = (lane & 7) << 4;   // read-side XOR
  char* pbase = (char*)&Pl[w][0];
  const int g = lane >> 4, cl = lane & 15;

  auto stage = [&](int buf, int s0) {
#pragma unroll
    for (int c = 0; c < 2; ++c) {
      int i = w * 2 + c;
      int ob = i * 1024 + lane * 16;
      int row = ob >> 7, colb = ob & 127;
      int src = colb ^ ((row & 7) << 4);   // inverse-swizzle the SOURCE
      gl_lds16((const char*)Kb + ((size_t)(s0 + row) * DM + h * DK) * 2 + src,
               (char*)&Ks[buf][0] + i * 1024);
      gl_lds16((const char*)Vt + ((size_t)(h * DK + row) * SEQ + s0) * 2 + src,
               (char*)&Vs[buf][0] + i * 1024);
    }
  };

  stage(0, 0);

  for (int t = 0; t < SEQ / 64; ++t) {
    const int cur = t & 1;
    __syncthreads();                 // stage(t) landed; buf[cur^1] reads done
    if (t < SEQ / 64 - 1) stage(cur ^ 1, (t + 1) * 64);

    const char* kbase = (const char*)&Ks[cur][0];
    const char* vbase = (const char*)&Vs[cur][0];

    // S' = Qs K^T (exp2-domain)
    f32x4 sc[4] = {};
    __builtin_amdgcn_s_setprio(1);
#pragma unroll
    for (int kk = 0; kk < 2; ++kk) {
      bf16x8 a = kk ? qf1 : qf0;
#pragma unroll
      for (int n = 0; n < 4; ++n) {
        bf16x8 b = *(const bf16x8*)(kbase + (n * 16 + cl) * 128 +
                                    ((kk * 64 + g * 16) ^ xk));
        sc[n] = __builtin_amdgcn_mfma_f32_16x16x32_bf16(a, b, sc[n], 0, 0, 0);
      }
    }
    __builtin_amdgcn_s_setprio(0);

    // group-shared max over this wave-group's 4 rows x 64 cols
    float lm = fmaxf(fmaxf(fmaxf(sc[0][0], sc[0][1]), fmaxf(sc[0][2], sc[0][3])),
                     fmaxf(fmaxf(sc[1][0], sc[1][1]), fmaxf(sc[1][2], sc[1][3])));
    lm = fmaxf(lm, fmaxf(fmaxf(fmaxf(sc[2][0], sc[2][1]), fmaxf(sc[2][2], sc[2][3])),
                         fmaxf(fmaxf(sc[3][0], sc[3][1]), fmaxf(sc[3][2], sc[3][3]))));
    lm = fmaxf(lm, __shfl_xor(lm, 1));
    lm = fmaxf(lm, __shfl_xor(lm, 2));
    lm = fmaxf(lm, __shfl_xor(lm, 4));
    lm = fmaxf(lm, __shfl_xor(lm, 8));
    if (!__all(lm <= m + 8.f)) {
      float mn = fmaxf(m, lm);
      float al = exp2f(m - mn);
      m = mn;
#pragma unroll
      for (int n = 0; n < 4; ++n) {
        o[n][0] *= al; o[n][1] *= al; o[n][2] *= al; o[n][3] *= al;
      }
      ol[0] *= al; ol[1] *= al; ol[2] *= al; ol[3] *= al;
    }

    // P = exp2(S'-m), pack pairs, one b64 store per row
#pragma unroll
    for (int r = 0; r < 4; ++r) {
      const int prow = g * 4 + r;
      float p0 = exp2f(sc[0][r] - m), p1 = exp2f(sc[1][r] - m);
      float p2 = exp2f(sc[2][r] - m), p3 = exp2f(sc[3][r] - m);
      uint32_t u0, u1;
      asm("v_cvt_pk_bf16_f32 %0, %1, %2" : "=v"(u0) : "v"(p0), "v"(p1));
      asm("v_cvt_pk_bf16_f32 %0, %1, %2" : "=v"(u1) : "v"(p2), "v"(p3));
      u32x2 uu; uu[0] = u0; uu[1] = u1;
      *(u32x2*)(pbase + prow * 128 + ((cl * 8) ^ ((prow & 7) << 4))) = uu;
    }

    // O += P V ; l += P 1
    __builtin_amdgcn_s_setprio(1);
#pragma unroll
    for (int kk = 0; kk < 2; ++kk) {
      bf16x8 pa = *(const bf16x8*)(pbase + cl * 128 + ((kk * 64 + g * 16) ^ xk));
      ol = __builtin_amdgcn_mfma_f32_16x16x32_bf16(pa, ones, ol, 0, 0, 0);
#pragma unroll
      for (int n = 0; n < 4; ++n) {
        bf16x8 vb = *(const bf16x8*)(vbase + (n * 16 + cl) * 128 +
                                     ((kk * 64 + g * 16) ^ xk));
        o[n] = __builtin_amdgcn_mfma_f32_16x16x32_bf16(pa, vb, o[n], 0, 0, 0);
      }
    }
    __builtin_amdgcn_s_setprio(0);
  }

#pragma unroll
  for (int r = 0; r < 4; ++r) {
    float inv = 1.f / ol[r];
    int row = qt * 64 + w * 16 + g * 4 + r;
#pragma unroll
    for (int n = 0; n < 4; ++n)
      ctx[(size_t)row * DM + h * DK + n * 16 + cl] = f2bf(o[n][r] * inv);
  }
}

extern "C" void kernel_launch(void* const* d_in, const int* in_sizes, int n_in,
                              void* d_out, int out_size, void* d_ws, size_t ws_size,
                              hipStream_t stream) {
  const float* x  = (const float*)d_in[0];
  const float* Wq = (const float*)d_in[1];
  const float* bq = (const float*)d_in[2];
  const float* Wk = (const float*)d_in[3];
  const float* bk = (const float*)d_in[4];
  const float* Wv = (const float*)d_in[5];
  const float* bv = (const float*)d_in[6];
  const float* Wo = (const float*)d_in[7];
  const float* bo = (const float*)d_in[8];

  char* ws = (char*)d_ws;
  short* xb  = (short*)(ws + (size_t)0);
  short* Wt  = (short*)(ws + ((size_t)8 << 20));
  short* Qb  = (short*)(ws + ((size_t)16 << 20));
  short* Kb  = (short*)(ws + ((size_t)24 << 20));
  short* Vb  = (short*)(ws + ((size_t)32 << 20));
  short* Vt  = (short*)(ws + ((size_t)40 << 20));
  short* ctx = (short*)(ws + ((size_t)48 << 20));

  cvt_x_k<<<2048, 256, 0, stream>>>(x, xb);
  cvt_wt_k<<<dim3(16, 16, 4), 256, 0, stream>>>(Wq, Wk, Wv, Wo, Wt);
  gemm_qkv<<<dim3(DM / 128, SEQ / 128, 3), 256, 0, stream>>>(xb, Wt, bq, bk, bv, Qb);
  trans_v_k<<<dim3(SEQ / 64, NH), 256, 0, stream>>>(Vb, Vt);
  attn_k<<<dim3(SEQ / 64, NH), 256, 0, stream>>>(Qb, Kb, Vt, ctx);
  gemm_out<<<dim3(DM / 128, SEQ / 128), 256, 0, stream>>>(
      ctx, Wt + (size_t)3 * (DM * DM), bo, (float*)d_out);
}